// Round 14
// baseline (97.368 us; speedup 1.0000x reference)
//
#include <hip/hip_runtime.h>
#include <cstdint>
#include <cstddef>

// ---------------- constants ----------------
#define NB    2
#define SEQ   2048
#define DIMC  1024
#define NH    16
#define HDIM  64
#define MROWS (NB*SEQ)     // 4096
#define NFEAT (3*DIMC)     // 3072
#define KVBLK 64

typedef _Float16 half8 __attribute__((ext_vector_type(8)));
typedef _Float16 half4 __attribute__((ext_vector_type(4)));
typedef _Float16 half2v __attribute__((ext_vector_type(2)));
typedef __fp16   fp16x2 __attribute__((ext_vector_type(2)));
typedef float    f32x4  __attribute__((ext_vector_type(4)));
typedef float    f32x16 __attribute__((ext_vector_type(16)));
typedef uint32_t u32x4v __attribute__((ext_vector_type(4)));

typedef const __attribute__((address_space(1))) void* gas_ptr;
typedef __attribute__((address_space(3))) void*       las_ptr;

__device__ __forceinline__ void gload_lds16(const void* g, void* l) {
    __builtin_amdgcn_global_load_lds((gas_ptr)g, (las_ptr)l, 16, 0, 0);
}

__device__ __forceinline__ int swz4(int r) { return (r ^ (r >> 2)) & 3; }

// v_exp_f32 computes 2^x directly (log2e folded into q-projection scale)
__device__ __forceinline__ float fast_exp2(float x) {
    float r;
    asm("v_exp_f32 %0, %1" : "=v"(r) : "v"(x));
    return r;
}

// pack two f32 -> two f16 (RTZ) in one instr, as a u32
__device__ __forceinline__ uint32_t pk_u32(float a, float b) {
    fp16x2 r = __builtin_amdgcn_cvt_pkrtz(a, b);
    return __builtin_bit_cast(uint32_t, r);
}

// ---------------- kernel 1a: x fp32 -> fp16 ----------------
__global__ __launch_bounds__(256) void k_convert_x(const float* __restrict__ x,
                                                   _Float16* __restrict__ x16) {
    int i = (blockIdx.x * 256 + threadIdx.x) * 4;
    float4 v = *reinterpret_cast<const float4*>(x + i);
    half4 h = { (_Float16)v.x, (_Float16)v.y, (_Float16)v.z, (_Float16)v.w };
    *reinterpret_cast<half4*>(x16 + i) = h;
}

// ---------------- kernel 1b: W[in][out] fp32 -> Wt[out][in] fp16 ----------------
__global__ __launch_bounds__(256) void k_transpose_w(const float* __restrict__ Wq,
                                                     const float* __restrict__ Wk,
                                                     const float* __restrict__ Wv,
                                                     _Float16* __restrict__ wt) {
    __shared__ float tile[64][65];
    const int bid  = blockIdx.x;          // 0..767
    const int midx = bid >> 8;            // which matrix
    const int t2   = bid & 255;           // 16x16 tiles of 64x64
    const int i0   = (t2 >> 4) * 64;      // input-row tile base
    const int o0   = (t2 & 15) * 64;      // output-feature tile base
    const float* W = (midx == 0) ? Wq : (midx == 1 ? Wk : Wv);
    const int tid  = threadIdx.x;
    #pragma unroll
    for (int p = 0; p < 4; ++p) {
        int id = p * 256 + tid;
        int r = id >> 4, c4 = (id & 15) * 4;
        float4 v = *reinterpret_cast<const float4*>(W + (size_t)(i0 + r) * DIMC + o0 + c4);
        tile[r][c4 + 0] = v.x; tile[r][c4 + 1] = v.y;
        tile[r][c4 + 2] = v.z; tile[r][c4 + 3] = v.w;
    }
    __syncthreads();
    #pragma unroll
    for (int p = 0; p < 4; ++p) {
        int id = p * 256 + tid;
        int oc = id >> 4, i4 = (id & 15) * 4;
        half4 h = { (_Float16)tile[i4 + 0][oc], (_Float16)tile[i4 + 1][oc],
                    (_Float16)tile[i4 + 2][oc], (_Float16)tile[i4 + 3][oc] };
        *reinterpret_cast<half4*>(wt + (size_t)(midx * DIMC + o0 + oc) * DIMC + i0 + i4) = h;
    }
}

// ---------------- kernel 2: fused QKV GEMM (tri-buffer, counted vmcnt) ----------------
__global__ __launch_bounds__(256) void k_qkv_gemm(
    const _Float16* __restrict__ x16, const _Float16* __restrict__ wt,
    const float* __restrict__ bq, const float* __restrict__ bk, const float* __restrict__ bv,
    _Float16* __restrict__ q16, _Float16* __restrict__ k16, _Float16* __restrict__ vt16)
{
    __shared__ __align__(16) char sraw[49152];
    const int tid = threadIdx.x;
    const int lane = tid & 63;
    const int w = tid >> 6, wm = w >> 1, wn = w & 1;
    const int lr = lane & 15, lg = lane >> 4;
    const int bn = blockIdx.x % (NFEAT / 128);
    const int bm = blockIdx.x / (NFEAT / 128);
    const int m0 = bm * 128, n0 = bn * 128;

    const f32x4 zero4 = {0.f, 0.f, 0.f, 0.f};
    f32x4 acc[4][4];
    #pragma unroll
    for (int i = 0; i < 4; ++i)
        #pragma unroll
        for (int j = 0; j < 4; ++j) acc[i][j] = zero4;

    auto stage = [&](int buf, int kt) {
        const int k0 = kt * 32;
        char* Adst = sraw + buf * 8192;
        char* Bdst = sraw + 24576 + buf * 8192;
        #pragma unroll
        for (int t = 0; t < 2; ++t) {
            int slot = t * 256 + tid;
            int row = slot >> 2, ch = slot & 3;
            int chg = ch ^ swz4(row);
            gload_lds16(x16 + (size_t)(m0 + row) * DIMC + k0 + chg * 8, Adst + slot * 16);
            gload_lds16(wt  + (size_t)(n0 + row) * DIMC + k0 + chg * 8, Bdst + slot * 16);
        }
    };

    stage(0, 0);
    stage(1, 1);
    for (int kt = 0; kt < DIMC / 32; ++kt) {
        if (kt < DIMC / 32 - 1) asm volatile("s_waitcnt vmcnt(4)" ::: "memory");
        else                    asm volatile("s_waitcnt vmcnt(0)" ::: "memory");
        __builtin_amdgcn_s_barrier();
        if (kt + 2 < DIMC / 32) stage((kt + 2) % 3, kt + 2);
        const char* Ab = sraw + (kt % 3) * 8192;
        const char* Bb = sraw + 24576 + (kt % 3) * 8192;
        half8 af[4], bf[4];
        #pragma unroll
        for (int mb = 0; mb < 4; ++mb) {
            int row = wm * 64 + mb * 16 + lr;
            af[mb] = *(const half8*)(Ab + row * 64 + ((lg ^ swz4(row)) << 4));
        }
        #pragma unroll
        for (int nb = 0; nb < 4; ++nb) {
            int col = wn * 64 + nb * 16 + lr;
            bf[nb] = *(const half8*)(Bb + col * 64 + ((lg ^ swz4(col)) << 4));
        }
        #pragma unroll
        for (int mb = 0; mb < 4; ++mb)
            #pragma unroll
            for (int nb = 0; nb < 4; ++nb)
                acc[mb][nb] = __builtin_amdgcn_mfma_f32_16x16x32_f16(af[mb], bf[nb], acc[mb][nb], 0, 0, 0);
    }

    const int sec = n0 >> 10;                 // 0=q 1=k 2=v
    const float* bias = (sec == 0) ? bq : (sec == 1 ? bk : bv);
    const float scl = (sec == 0) ? 0.125f * 1.44269504088896f : 1.0f;
    float bfv[4];
    #pragma unroll
    for (int nb = 0; nb < 4; ++nb)
        bfv[nb] = bias[(n0 & 1023) + wn * 64 + nb * 16 + lr];

    if (sec < 2) {
        _Float16* dst = (sec == 0) ? q16 : k16;
        #pragma unroll
        for (int mb = 0; mb < 4; ++mb)
            #pragma unroll
            for (int i2 = 0; i2 < 4; ++i2) {
                int rg = m0 + wm * 64 + mb * 16 + lg * 4 + i2;
                int bb = rg >> 11, nn = rg & (SEQ - 1);
                #pragma unroll
                for (int nb = 0; nb < 4; ++nb) {
                    int f1 = (n0 & 1023) + wn * 64 + nb * 16 + lr;
                    int hh = f1 >> 6, dd = f1 & 63;
                    dst[((size_t)(bb * NH + hh) * SEQ + nn) * HDIM + dd] =
                        (_Float16)((acc[mb][nb][i2] + bfv[nb]) * scl);
                }
            }
    } else {
        __syncthreads();
        char* lt = sraw;                       // [128 cols][136 halfs] stride 272B
        #pragma unroll
        for (int mb = 0; mb < 4; ++mb)
            #pragma unroll
            for (int nb = 0; nb < 4; ++nb) {
                int c  = wn * 64 + nb * 16 + lr;
                int r0 = wm * 64 + mb * 16 + lg * 4;
                half4 hv = { (_Float16)(acc[mb][nb][0] + bfv[nb]),
                             (_Float16)(acc[mb][nb][1] + bfv[nb]),
                             (_Float16)(acc[mb][nb][2] + bfv[nb]),
                             (_Float16)(acc[mb][nb][3] + bfv[nb]) };
                *(half4*)(lt + c * 272 + r0 * 2) = hv;
            }
        __syncthreads();
        #pragma unroll
        for (int p = 0; p < 8; ++p) {
            int id = p * 256 + tid;            // 0..2047
            int c = id >> 4, r8 = (id & 15) * 8;
            half8 hv = *(const half8*)(lt + c * 272 + r8 * 2);
            int f1 = (n0 & 1023) + c;
            int hh = f1 >> 6, dd = f1 & 63;
            int rg = m0 + r8;
            int bb = rg >> 11, nn = rg & (SEQ - 1);
            *(half8*)(vt16 + ((size_t)(bb * NH + hh) * HDIM + dd) * SEQ + nn) = hv;
        }
    }
}

// ---------------- kernel 3: flash attention (v12, 32x32 MFMA, in-register P) ----------------
// 512 thr = 8 waves, QBLK=128, split-KV wave pairs (waves 0-3: tiles 0-15,
// waves 4-7: 16-31, same q). Wave owns 32 q-rows as ONE 32-wide MFMA N-dim.
// QK^T: 8x mfma_32x32x16 (swapped: A=K,B=Q) -> S^T col=q(lane&31),
// row=k=(reg&3)+8*(reg>>2)+4*(lane>>5). Max-free softmax (P=2^s), then the
// P->PV A-fragment conversion is IN-REGISTER: cvt_pkrtz pairs + half-exchange
// across lane halves (shfl_xor 32 + select). PV: 8x mfma_32x32x16. No P LDS
// roundtrip, all LDS reads are conflict-free b128.
__global__ __launch_bounds__(512, 4) void k_attn(
    const _Float16* __restrict__ q16, const _Float16* __restrict__ k16,
    const _Float16* __restrict__ vt16, float* __restrict__ out)
{
    __shared__ __align__(16) char lds[65536];
    // [0,16K) K_A dbuf | [16K,32K) K_B dbuf | [32K,48K) V_A dbuf | [48K,64K) V_B dbuf
    // epilogue exchange reuses [0, 33792)
    const int tid = threadIdx.x, lane = tid & 63, w = tid >> 6;
    const int ln = lane & 31, h = lane >> 5;
    const int sub = w >> 2;                   // KV half
    const int qg  = w & 3;                    // 32-row q sub-block
    // XCD-bijective swizzle (512 % 8 == 0)
    const int swz = (blockIdx.x & 7) * 64 + (blockIdx.x >> 3);
    const int bh = swz >> 4;                  // 0..31
    const int qt = swz & 15;                  // 0..15
    const int qrow0 = qt * 128 + qg * 32;
    const _Float16* qh = q16 + (size_t)bh * SEQ * HDIM;
    const _Float16* kh = k16 + (size_t)bh * SEQ * HDIM;
    const _Float16* vh = vt16 + (size_t)bh * HDIM * SEQ;

    // staging: 512 threads x 4 x 16B = 32KB per phase (K/V for both streams)
    const int srow = tid >> 3;                // 0..63
    const int scg  = (tid & 7) ^ (srow & 7);  // inverse-swizzled source chunk

    auto stageKV = [&](int buf, int t) {
        const int jA = t * KVBLK, jB = (16 + t) * KVBLK;
        gload_lds16(kh + (size_t)(jA + srow) * HDIM + scg * 8,
                    lds + buf * 8192 + tid * 16);
        gload_lds16(kh + (size_t)(jB + srow) * HDIM + scg * 8,
                    lds + 16384 + buf * 8192 + tid * 16);
        gload_lds16(vh + (size_t)srow * SEQ + jA + scg * 8,
                    lds + 32768 + buf * 8192 + tid * 16);
        gload_lds16(vh + (size_t)srow * SEQ + jB + scg * 8,
                    lds + 49152 + buf * 8192 + tid * 16);
    };

    // Q fragments (B-operand): lane holds Q[q=qrow0+ln][kdb*16 + 8h .. +7]
    half8 aq[4];
    #pragma unroll
    for (int kdb = 0; kdb < 4; ++kdb)
        aq[kdb] = *(const half8*)(qh + (size_t)(qrow0 + ln) * HDIM + kdb * 16 + h * 8);

    f32x16 oacc[2];
    #pragma unroll
    for (int r = 0; r < 16; ++r) { oacc[0][r] = 0.f; oacc[1][r] = 0.f; }
    float l_p = 0.f;

    stageKV(0, 0);
    for (int t = 0; t < 16; ++t) {
        __syncthreads();                      // buf[t&1] ready (drains vmcnt)
        if (t + 1 < 16) stageKV((t + 1) & 1, t + 1);
        const char* Kb = lds + sub * 16384 + (t & 1) * 8192;
        const char* Vb = lds + 32768 + sub * 16384 + (t & 1) * 8192;

        // QK^T: s[kb] = S^T[k=kb*32+..][q]; A=K-frag (row=kb*32+ln, kd 8h..+7)
        f32x16 s[2];
        #pragma unroll
        for (int r = 0; r < 16; ++r) { s[0][r] = 0.f; s[1][r] = 0.f; }
        __builtin_amdgcn_s_setprio(1);
        #pragma unroll
        for (int kb = 0; kb < 2; ++kb) {
            int row = kb * 32 + ln;
            #pragma unroll
            for (int kdb = 0; kdb < 4; ++kdb) {
                half8 kf = *(const half8*)(Kb + row * 128 + (((kdb * 2 + h) ^ (ln & 7)) << 4));
                s[kb] = __builtin_amdgcn_mfma_f32_32x32x16_f16(kf, aq[kdb], s[kb], 0, 0, 0);
            }
        }
        __builtin_amdgcn_s_setprio(0);

        // max-free softmax: P = 2^s ; accumulate l per lane (q = qrow0+ln)
        #pragma unroll
        for (int kb = 0; kb < 2; ++kb)
            #pragma unroll
            for (int r = 0; r < 16; ++r) {
                s[kb][r] = fast_exp2(s[kb][r]);
                l_p += s[kb][r];
            }

        // pack P -> PV A-fragments in registers.
        // c[i] = f16 pair at k = crow(2i),crow(2i+1); crow(r)=(r&3)+8*(r>>2)+4h.
        // Half-exchange (across lane halves) builds 8-consecutive-k fragments:
        //   X'(lo,hi) = h ? shfl32(hi) : lo ; Y'(lo,hi) = h ? hi : shfl32(lo)
        uint32_t pa[16];
        #pragma unroll
        for (int kb = 0; kb < 2; ++kb) {
            uint32_t c0 = pk_u32(s[kb][0],  s[kb][1]);
            uint32_t c1 = pk_u32(s[kb][2],  s[kb][3]);
            uint32_t c2 = pk_u32(s[kb][4],  s[kb][5]);
            uint32_t c3 = pk_u32(s[kb][6],  s[kb][7]);
            uint32_t c4 = pk_u32(s[kb][8],  s[kb][9]);
            uint32_t c5 = pk_u32(s[kb][10], s[kb][11]);
            uint32_t c6 = pk_u32(s[kb][12], s[kb][13]);
            uint32_t c7 = pk_u32(s[kb][14], s[kb][15]);
            uint32_t c0s = (uint32_t)__shfl_xor((int)c0, 32);
            uint32_t c1s = (uint32_t)__shfl_xor((int)c1, 32);
            uint32_t c2s = (uint32_t)__shfl_xor((int)c2, 32);
            uint32_t c3s = (uint32_t)__shfl_xor((int)c3, 32);
            uint32_t c4s = (uint32_t)__shfl_xor((int)c4, 32);
            uint32_t c5s = (uint32_t)__shfl_xor((int)c5, 32);
            uint32_t c6s = (uint32_t)__shfl_xor((int)c6, 32);
            uint32_t c7s = (uint32_t)__shfl_xor((int)c7, 32);
            pa[kb * 8 + 0] = h ? c2s : c0;    // pair k(8h+0,8h+1)
            pa[kb * 8 + 1] = h ? c3s : c1;    // pair k(8h+2,8h+3)
            pa[kb * 8 + 2] = h ? c2  : c0s;   // pair k(8h+4,8h+5)
            pa[kb * 8 + 3] = h ? c3  : c1s;   // pair k(8h+6,8h+7)
            pa[kb * 8 + 4] = h ? c6s : c4;
            pa[kb * 8 + 5] = h ? c7s : c5;
            pa[kb * 8 + 6] = h ? c6  : c4s;
            pa[kb * 8 + 7] = h ? c7  : c5s;
        }

        // PV: 2 d-blocks x 4 k-blocks of 16; B = V^T[d=db*32+ln][16 seq], b128
        __builtin_amdgcn_s_setprio(1);
        #pragma unroll
        for (int db = 0; db < 2; ++db) {
            int row = db * 32 + ln;
            #pragma unroll
            for (int kbp = 0; kbp < 4; ++kbp) {
                half8 vf = *(const half8*)(Vb + row * 128 + (((kbp * 2 + h) ^ (ln & 7)) << 4));
                u32x4v pu = { pa[kbp * 4 + 0], pa[kbp * 4 + 1], pa[kbp * 4 + 2], pa[kbp * 4 + 3] };
                half8 pa8 = __builtin_bit_cast(half8, pu);
                oacc[db] = __builtin_amdgcn_mfma_f32_32x32x16_f16(pa8, vf, oacc[db], 0, 0, 0);
            }
        }
        __builtin_amdgcn_s_setprio(0);
    }

    // ---- cross-pair reduction: wave w (sub=1) -> wave w^4 (sub=0) ----
    __syncthreads();                          // all tile compute done
    float* xch = (float*)lds;                 // 4 qg x 2112 floats = 33792 B
    if (sub == 1) {
        float* sl = xch + qg * 2112;
        #pragma unroll
        for (int db = 0; db < 2; ++db)
            #pragma unroll
            for (int r = 0; r < 16; ++r)
                sl[(db * 16 + r) * 64 + lane] = oacc[db][r];
        sl[32 * 64 + lane] = l_p;
    }
    __syncthreads();
    if (sub == 0) {
        float* sl = xch + qg * 2112;
        #pragma unroll
        for (int db = 0; db < 2; ++db)
            #pragma unroll
            for (int r = 0; r < 16; ++r)
                oacc[db][r] += sl[(db * 16 + r) * 64 + lane];
        l_p += sl[32 * 64 + lane];
        l_p += __shfl_xor(l_p, 32);           // combine k-halves -> l[q=ln]
        float rl = 1.0f / l_p;

        const int bb = bh >> 4, hh = bh & 15;
        #pragma unroll
        for (int r = 0; r < 16; ++r) {
            int qloc = (r & 3) + 8 * (r >> 2) + 4 * h;
            float rlq = __shfl(rl, qloc);
            int nn = qrow0 + qloc;
            out[((size_t)bb * SEQ + nn) * DIMC + hh * HDIM + 0  + ln] = oacc[0][r] * rlq;
            out[((size_t)bb * SEQ + nn) * DIMC + hh * HDIM + 32 + ln] = oacc[1][r] * rlq;
        }
    }
}

// ---------------- launcher ----------------
extern "C" void kernel_launch(void* const* d_in, const int* in_sizes, int n_in,
                              void* d_out, int out_size, void* d_ws, size_t ws_size,
                              hipStream_t stream)
{
    const float* x  = (const float*)d_in[0];
    const float* Wq = (const float*)d_in[1];
    const float* bq = (const float*)d_in[2];
    const float* Wk = (const float*)d_in[3];
    const float* bk = (const float*)d_in[4];
    const float* Wv = (const float*)d_in[5];
    const float* bv = (const float*)d_in[6];
    float* out = (float*)d_out;

    char* ws = (char*)d_ws;
    _Float16* x16  = (_Float16*)ws;                          //  8 MB: [4096][1024]
    _Float16* wt   = (_Float16*)(ws + ((size_t)8  << 20));   //  6 MB: [3072][1024] (W^T)
    _Float16* q16  = (_Float16*)(ws + ((size_t)14 << 20));   //  8 MB: [b,h,n,d]
    _Float16* k16  = (_Float16*)(ws + ((size_t)22 << 20));   //  8 MB: [b,h,n,d]
    _Float16* vt16 = (_Float16*)(ws + ((size_t)30 << 20));   //  8 MB: [b,h,d,n]

    k_convert_x<<<MROWS * DIMC / 1024, 256, 0, stream>>>(x, x16);
    k_transpose_w<<<3 * 256, 256, 0, stream>>>(Wq, Wk, Wv, wt);
    k_qkv_gemm<<<(MROWS / 128) * (NFEAT / 128), 256, 0, stream>>>(x16, wt, bq, bk, bv,
                                                                  q16, k16, vt16);
    k_attn<<<32 * (SEQ / 128), 512, 0, stream>>>(q16, k16, vt16, out);
}

// Round 15
// 91.256 us; speedup vs baseline: 1.0670x; 1.0670x over previous
//
#include <hip/hip_runtime.h>
#include <cstdint>
#include <cstddef>

// ---------------- constants ----------------
#define NB    2
#define SEQ   2048
#define DIMC  1024
#define NH    16
#define HDIM  64
#define MROWS (NB*SEQ)     // 4096
#define NFEAT (3*DIMC)     // 3072
#define KVBLK 64

typedef _Float16 half8 __attribute__((ext_vector_type(8)));
typedef _Float16 half4 __attribute__((ext_vector_type(4)));
typedef _Float16 half2v __attribute__((ext_vector_type(2)));
typedef __fp16   fp16x2 __attribute__((ext_vector_type(2)));
typedef float    f32x4 __attribute__((ext_vector_type(4)));

typedef const __attribute__((address_space(1))) void* gas_ptr;
typedef __attribute__((address_space(3))) void*       las_ptr;

__device__ __forceinline__ void gload_lds16(const void* g, void* l) {
    __builtin_amdgcn_global_load_lds((gas_ptr)g, (las_ptr)l, 16, 0, 0);
}

__device__ __forceinline__ int swz4(int r) { return (r ^ (r >> 2)) & 3; }

// v_exp_f32 computes 2^x directly (log2e folded into q-projection scale)
__device__ __forceinline__ float fast_exp2(float x) {
    float r;
    asm("v_exp_f32 %0, %1" : "=v"(r) : "v"(x));
    return r;
}

// pack two f32 -> two f16 (RTZ) in one instr; bit-cast to _Float16 vector
__device__ __forceinline__ half2v pk_f16(float a, float b) {
    fp16x2 r = __builtin_amdgcn_cvt_pkrtz(a, b);
    return __builtin_bit_cast(half2v, r);
}

// ---------------- kernel 1: fused input prep ----------------
// blocks [0,4096): x fp32 -> fp16 (vectorized)
// blocks [4096,4864): W[in][out] fp32 -> Wt[out][in] fp16 (LDS transpose)
__global__ __launch_bounds__(256) void k_prep(const float* __restrict__ x,
                                              const float* __restrict__ Wq,
                                              const float* __restrict__ Wk,
                                              const float* __restrict__ Wv,
                                              _Float16* __restrict__ x16,
                                              _Float16* __restrict__ wt) {
    __shared__ float tile[64][65];
    const int tid = threadIdx.x;
    if (blockIdx.x < 4096) {
        int i = (blockIdx.x * 256 + tid) * 4;
        float4 v = *reinterpret_cast<const float4*>(x + i);
        half4 h = { (_Float16)v.x, (_Float16)v.y, (_Float16)v.z, (_Float16)v.w };
        *reinterpret_cast<half4*>(x16 + i) = h;
        return;
    }
    const int bid  = blockIdx.x - 4096;   // 0..767
    const int midx = bid >> 8;            // which matrix
    const int t2   = bid & 255;           // 16x16 tiles of 64x64
    const int i0   = (t2 >> 4) * 64;      // input-row tile base
    const int o0   = (t2 & 15) * 64;      // output-feature tile base
    const float* W = (midx == 0) ? Wq : (midx == 1 ? Wk : Wv);
    #pragma unroll
    for (int p = 0; p < 4; ++p) {
        int id = p * 256 + tid;
        int r = id >> 4, c4 = (id & 15) * 4;
        float4 v = *reinterpret_cast<const float4*>(W + (size_t)(i0 + r) * DIMC + o0 + c4);
        tile[r][c4 + 0] = v.x; tile[r][c4 + 1] = v.y;
        tile[r][c4 + 2] = v.z; tile[r][c4 + 3] = v.w;
    }
    __syncthreads();
    #pragma unroll
    for (int p = 0; p < 4; ++p) {
        int id = p * 256 + tid;
        int oc = id >> 4, i4 = (id & 15) * 4;
        half4 h = { (_Float16)tile[i4 + 0][oc], (_Float16)tile[i4 + 1][oc],
                    (_Float16)tile[i4 + 2][oc], (_Float16)tile[i4 + 3][oc] };
        *reinterpret_cast<half4*>(wt + (size_t)(midx * DIMC + o0 + oc) * DIMC + i0 + i4) = h;
    }
}

// ---------------- kernel 2: fused QKV GEMM (tri-buffer, counted vmcnt, XCD swizzle) ----------------
__global__ __launch_bounds__(256) void k_qkv_gemm(
    const _Float16* __restrict__ x16, const _Float16* __restrict__ wt,
    const float* __restrict__ bq, const float* __restrict__ bk, const float* __restrict__ bv,
    _Float16* __restrict__ q16, _Float16* __restrict__ k16, _Float16* __restrict__ vt16)
{
    __shared__ __align__(16) char sraw[49152];   // A 3x8KB | B 3x8KB (24K..48K); v-transpose reuses [0,34K)
    const int tid = threadIdx.x;
    const int lane = tid & 63;
    const int w = tid >> 6, wm = w >> 1, wn = w & 1;
    const int lr = lane & 15, lg = lane >> 4;
    // XCD-bijective swizzle (768 % 8 == 0): each XCD gets 4 A-panels x 24 B-cols
    const int swzb = (blockIdx.x & 7) * 96 + (blockIdx.x >> 3);
    const int bn = swzb % (NFEAT / 128);
    const int bm = swzb / (NFEAT / 128);
    const int m0 = bm * 128, n0 = bn * 128;

    const f32x4 zero4 = {0.f, 0.f, 0.f, 0.f};
    f32x4 acc[4][4];
    #pragma unroll
    for (int i = 0; i < 4; ++i)
        #pragma unroll
        for (int j = 0; j < 4; ++j) acc[i][j] = zero4;

    auto stage = [&](int buf, int kt) {
        const int k0 = kt * 32;
        char* Adst = sraw + buf * 8192;
        char* Bdst = sraw + 24576 + buf * 8192;
        #pragma unroll
        for (int t = 0; t < 2; ++t) {
            int slot = t * 256 + tid;
            int row = slot >> 2, ch = slot & 3;
            int chg = ch ^ swz4(row);
            gload_lds16(x16 + (size_t)(m0 + row) * DIMC + k0 + chg * 8, Adst + slot * 16);
            gload_lds16(wt  + (size_t)(n0 + row) * DIMC + k0 + chg * 8, Bdst + slot * 16);
        }
    };

    stage(0, 0);
    stage(1, 1);
    for (int kt = 0; kt < DIMC / 32; ++kt) {
        if (kt < DIMC / 32 - 1) asm volatile("s_waitcnt vmcnt(4)" ::: "memory");
        else                    asm volatile("s_waitcnt vmcnt(0)" ::: "memory");
        __builtin_amdgcn_s_barrier();
        if (kt + 2 < DIMC / 32) stage((kt + 2) % 3, kt + 2);
        const char* Ab = sraw + (kt % 3) * 8192;
        const char* Bb = sraw + 24576 + (kt % 3) * 8192;
        half8 af[4], bf[4];
        #pragma unroll
        for (int mb = 0; mb < 4; ++mb) {
            int row = wm * 64 + mb * 16 + lr;
            af[mb] = *(const half8*)(Ab + row * 64 + ((lg ^ swz4(row)) << 4));
        }
        #pragma unroll
        for (int nb = 0; nb < 4; ++nb) {
            int col = wn * 64 + nb * 16 + lr;
            bf[nb] = *(const half8*)(Bb + col * 64 + ((lg ^ swz4(col)) << 4));
        }
        #pragma unroll
        for (int mb = 0; mb < 4; ++mb)
            #pragma unroll
            for (int nb = 0; nb < 4; ++nb)
                acc[mb][nb] = __builtin_amdgcn_mfma_f32_16x16x32_f16(af[mb], bf[nb], acc[mb][nb], 0, 0, 0);
    }

    const int sec = n0 >> 10;                 // 0=q 1=k 2=v
    const float* bias = (sec == 0) ? bq : (sec == 1 ? bk : bv);
    const float scl = (sec == 0) ? 0.125f * 1.44269504088896f : 1.0f;
    float bfv[4];
    #pragma unroll
    for (int nb = 0; nb < 4; ++nb)
        bfv[nb] = bias[(n0 & 1023) + wn * 64 + nb * 16 + lr];

    if (sec < 2) {
        _Float16* dst = (sec == 0) ? q16 : k16;
        #pragma unroll
        for (int mb = 0; mb < 4; ++mb)
            #pragma unroll
            for (int i2 = 0; i2 < 4; ++i2) {
                int rg = m0 + wm * 64 + mb * 16 + lg * 4 + i2;
                int bb = rg >> 11, nn = rg & (SEQ - 1);
                #pragma unroll
                for (int nb = 0; nb < 4; ++nb) {
                    int f1 = (n0 & 1023) + wn * 64 + nb * 16 + lr;
                    int hh = f1 >> 6, dd = f1 & 63;
                    dst[((size_t)(bb * NH + hh) * SEQ + nn) * HDIM + dd] =
                        (_Float16)((acc[mb][nb][i2] + bfv[nb]) * scl);
                }
            }
    } else {
        __syncthreads();
        char* lt = sraw;                       // [128 cols][136 halfs] stride 272B
        #pragma unroll
        for (int mb = 0; mb < 4; ++mb)
            #pragma unroll
            for (int nb = 0; nb < 4; ++nb) {
                int c  = wn * 64 + nb * 16 + lr;
                int r0 = wm * 64 + mb * 16 + lg * 4;
                half4 hv = { (_Float16)(acc[mb][nb][0] + bfv[nb]),
                             (_Float16)(acc[mb][nb][1] + bfv[nb]),
                             (_Float16)(acc[mb][nb][2] + bfv[nb]),
                             (_Float16)(acc[mb][nb][3] + bfv[nb]) };
                *(half4*)(lt + c * 272 + r0 * 2) = hv;
            }
        __syncthreads();
        #pragma unroll
        for (int p = 0; p < 8; ++p) {
            int id = p * 256 + tid;            // 0..2047
            int c = id >> 4, r8 = (id & 15) * 8;
            half8 hv = *(const half8*)(lt + c * 272 + r8 * 2);
            int f1 = (n0 & 1023) + c;
            int hh = f1 >> 6, dd = f1 & 63;
            int rg = m0 + r8;
            int bb = rg >> 11, nn = rg & (SEQ - 1);
            *(half8*)(vt16 + ((size_t)(bb * NH + hh) * HDIM + dd) * SEQ + nn) = hv;
        }
    }
}

// ---------------- kernel 3: flash attention (round-12 proven best) ----------------
// 512 thr = 8 waves, QBLK=128, split-KV wave pairs (waves 0-3: tiles 0-15,
// waves 4-7: tiles 16-31, same q; each wave: two 16-row q-groups). Max-free
// softmax (P=2^s unnormalized, divide at end). Conflict-free P roundtrip.
__global__ __launch_bounds__(512, 4) void k_attn(
    const _Float16* __restrict__ q16, const _Float16* __restrict__ k16,
    const _Float16* __restrict__ vt16, float* __restrict__ out)
{
    __shared__ __align__(16) char lds[81920];
    // [0,16K) K_A dbuf | [16K,32K) K_B dbuf | [32K,48K) V_A dbuf | [48K,64K) V_B dbuf
    // [64K,80K) P: 8 waves x 2KB (reused by both q-groups sequentially)
    // epilogue exchange reuses [0, 40960)
    const int tid = threadIdx.x, lane = tid & 63, w = tid >> 6;
    const int lr = lane & 15, lg = lane >> 4;
    const int sub = w >> 2;                   // KV half
    const int qg  = w & 3;                    // 32-row q sub-block
    // XCD-bijective swizzle (512 % 8 == 0)
    const int swz = (blockIdx.x & 7) * 64 + (blockIdx.x >> 3);
    const int bh = swz >> 4;                  // 0..31
    const int qt = swz & 15;                  // 0..15
    const int qrow0 = qt * 128 + qg * 32;
    const _Float16* qh = q16 + (size_t)bh * SEQ * HDIM;
    const _Float16* kh = k16 + (size_t)bh * SEQ * HDIM;
    const _Float16* vh = vt16 + (size_t)bh * HDIM * SEQ;
    char* pl = lds + 65536 + w * 2048;
    const int rb = lr >> 3;                   // row bit 3 -> 8B slot parity

    // staging: 512 threads x 4 x 16B = 32KB per phase (K/V for both streams)
    const int srow = tid >> 3;                // 0..63
    const int scg  = (tid & 7) ^ (srow & 7);  // inverse-swizzled source chunk

    auto stageKV = [&](int buf, int t) {
        const int jA = t * KVBLK, jB = (16 + t) * KVBLK;
        gload_lds16(kh + (size_t)(jA + srow) * HDIM + scg * 8,
                    lds + buf * 8192 + tid * 16);
        gload_lds16(kh + (size_t)(jB + srow) * HDIM + scg * 8,
                    lds + 16384 + buf * 8192 + tid * 16);
        gload_lds16(vh + (size_t)srow * SEQ + jA + scg * 8,
                    lds + 32768 + buf * 8192 + tid * 16);
        gload_lds16(vh + (size_t)srow * SEQ + jB + scg * 8,
                    lds + 49152 + buf * 8192 + tid * 16);
    };

    half8 aq[2][2];
    #pragma unroll
    for (int g = 0; g < 2; ++g)
        #pragma unroll
        for (int kc = 0; kc < 2; ++kc)
            aq[g][kc] = *(const half8*)(qh + (size_t)(qrow0 + g * 16 + lr) * HDIM + kc * 32 + lg * 8);

    const f32x4 zero4 = {0.f, 0.f, 0.f, 0.f};
    f32x4 l4[2] = { zero4, zero4 };
    f32x4 oacc[2][4];
    #pragma unroll
    for (int g = 0; g < 2; ++g)
        #pragma unroll
        for (int i = 0; i < 4; ++i) oacc[g][i] = zero4;

    stageKV(0, 0);
    for (int t = 0; t < 16; ++t) {
        __syncthreads();                      // buf[t&1] ready (drains vmcnt)
        if (t + 1 < 16) stageKV((t + 1) & 1, t + 1);
        const char* Kb = lds + sub * 16384 + (t & 1) * 8192;
        const char* Vb = lds + 32768 + sub * 16384 + (t & 1) * 8192;

        // swapped QK^T for both q-groups; K fragments read ONCE
        f32x4 s0[4], s1[4];
        __builtin_amdgcn_s_setprio(1);
        #pragma unroll
        for (int jb = 0; jb < 4; ++jb) {
            int row = jb * 16 + lr;
            half8 k0 = *(const half8*)(Kb + row * 128 + (((0 + lg) ^ (row & 7)) << 4));
            half8 k1 = *(const half8*)(Kb + row * 128 + (((4 + lg) ^ (row & 7)) << 4));
            f32x4 a0 = __builtin_amdgcn_mfma_f32_16x16x32_f16(k0, aq[0][0], zero4, 0, 0, 0);
            f32x4 a1 = __builtin_amdgcn_mfma_f32_16x16x32_f16(k0, aq[1][0], zero4, 0, 0, 0);
            a0 = __builtin_amdgcn_mfma_f32_16x16x32_f16(k1, aq[0][1], a0, 0, 0, 0);
            a1 = __builtin_amdgcn_mfma_f32_16x16x32_f16(k1, aq[1][1], a1, 0, 0, 0);
            s0[jb] = a0; s1[jb] = a1;
        }
        __builtin_amdgcn_s_setprio(0);

        // group 0: max-free softmax + pack + P write
        #pragma unroll
        for (int jb = 0; jb < 4; ++jb) {
            #pragma unroll
            for (int i = 0; i < 4; ++i) s0[jb][i] = fast_exp2(s0[jb][i]);
            l4[0] += s0[jb];
            half2v w0 = pk_f16(s0[jb][0], s0[jb][1]);
            half2v w1 = pk_f16(s0[jb][2], s0[jb][3]);
            half4 pk = { w0.x, w0.y, w1.x, w1.y };
            *(half4*)(pl + lr * 128 + (((jb * 2 + (lg >> 1)) ^ (lr & 7)) << 4)
                      + (((lg & 1) ^ rb) << 3)) = pk;
        }
        // group 1: softmax + pack to regs (write after g0's P is read back)
        half4 pk1[4];
        #pragma unroll
        for (int jb = 0; jb < 4; ++jb) {
            #pragma unroll
            for (int i = 0; i < 4; ++i) s1[jb][i] = fast_exp2(s1[jb][i]);
            l4[1] += s1[jb];
            half2v w0 = pk_f16(s1[jb][0], s1[jb][1]);
            half2v w1 = pk_f16(s1[jb][2], s1[jb][3]);
            pk1[jb] = half4{ w0.x, w0.y, w1.x, w1.y };
        }
        asm volatile("s_waitcnt lgkmcnt(0)" ::: "memory");
        const char* prow = pl + lr * 128;
        half8 ap[2][2];
        {
            half4 l0 = *(const half4*)(prow + (((0 + lg) ^ (lr & 7)) << 4) + (rb << 3));
            half4 h0 = *(const half4*)(prow + (((0 + lg) ^ (lr & 7)) << 4) + ((1 ^ rb) << 3));
            half4 l1 = *(const half4*)(prow + (((4 + lg) ^ (lr & 7)) << 4) + (rb << 3));
            half4 h1 = *(const half4*)(prow + (((4 + lg) ^ (lr & 7)) << 4) + ((1 ^ rb) << 3));
            ap[0][0] = half8{ l0.x, l0.y, l0.z, l0.w, h0.x, h0.y, h0.z, h0.w };
            ap[0][1] = half8{ l1.x, l1.y, l1.z, l1.w, h1.x, h1.y, h1.z, h1.w };
        }
        // write group 1 P (same buffer; DS pipe is in-order within a wave)
        #pragma unroll
        for (int jb = 0; jb < 4; ++jb)
            *(half4*)(pl + lr * 128 + (((jb * 2 + (lg >> 1)) ^ (lr & 7)) << 4)
                      + (((lg & 1) ^ rb) << 3)) = pk1[jb];
        asm volatile("s_waitcnt lgkmcnt(0)" ::: "memory");
        {
            half4 l0 = *(const half4*)(prow + (((0 + lg) ^ (lr & 7)) << 4) + (rb << 3));
            half4 h0 = *(const half4*)(prow + (((0 + lg) ^ (lr & 7)) << 4) + ((1 ^ rb) << 3));
            half4 l1 = *(const half4*)(prow + (((4 + lg) ^ (lr & 7)) << 4) + (rb << 3));
            half4 h1 = *(const half4*)(prow + (((4 + lg) ^ (lr & 7)) << 4) + ((1 ^ rb) << 3));
            ap[1][0] = half8{ l0.x, l0.y, l0.z, l0.w, h0.x, h0.y, h0.z, h0.w };
            ap[1][1] = half8{ l1.x, l1.y, l1.z, l1.w, h1.x, h1.y, h1.z, h1.w };
        }
        // PV: V fragments read lazily (once, feed both groups)
        __builtin_amdgcn_s_setprio(1);
        #pragma unroll
        for (int db = 0; db < 4; ++db) {
            int row = db * 16 + lr;
            half8 vf0 = *(const half8*)(Vb + row * 128 + (((0 + lg) ^ (row & 7)) << 4));
            half8 vf1 = *(const half8*)(Vb + row * 128 + (((4 + lg) ^ (row & 7)) << 4));
            oacc[0][db] = __builtin_amdgcn_mfma_f32_16x16x32_f16(ap[0][0], vf0, oacc[0][db], 0, 0, 0);
            oacc[1][db] = __builtin_amdgcn_mfma_f32_16x16x32_f16(ap[1][0], vf0, oacc[1][db], 0, 0, 0);
            oacc[0][db] = __builtin_amdgcn_mfma_f32_16x16x32_f16(ap[0][1], vf1, oacc[0][db], 0, 0, 0);
            oacc[1][db] = __builtin_amdgcn_mfma_f32_16x16x32_f16(ap[1][1], vf1, oacc[1][db], 0, 0, 0);
        }
        __builtin_amdgcn_s_setprio(0);
    }

    // ---- cross-pair reduction: wave w (sub=1) -> wave w^4 (sub=0) ----
    __syncthreads();                          // all tile compute done
    char* xch = lds;                          // [0, 8*5120) = 40960B
    if (sub == 1) {
        char* sl = xch + (qg * 2) * 5120;
        #pragma unroll
        for (int g = 0; g < 2; ++g) {
            #pragma unroll
            for (int db = 0; db < 4; ++db)
                *(f32x4*)(sl + g * 5120 + db * 1024 + lane * 16) = oacc[g][db];
            *(f32x4*)(sl + g * 5120 + 4096 + lane * 16) = l4[g];
        }
    }
    __syncthreads();
    if (sub == 0) {
        char* sl = xch + (qg * 2) * 5120;
        #pragma unroll
        for (int g = 0; g < 2; ++g) {
            #pragma unroll
            for (int db = 0; db < 4; ++db)
                oacc[g][db] += *(const f32x4*)(sl + g * 5120 + db * 1024 + lane * 16);
            l4[g] += *(const f32x4*)(sl + g * 5120 + 4096 + lane * 16);
        }
        const int bb = bh >> 4, hh = bh & 15;
        #pragma unroll
        for (int g = 0; g < 2; ++g) {
            float l_i = (l4[g][0] + l4[g][1]) + (l4[g][2] + l4[g][3]);
            l_i += __shfl_xor(l_i, 16);
            l_i += __shfl_xor(l_i, 32);
            float rlq[4];
            #pragma unroll
            for (int i = 0; i < 4; ++i)
                rlq[i] = 1.0f / __shfl(l_i, lg * 4 + i);
            #pragma unroll
            for (int db = 0; db < 4; ++db)
                #pragma unroll
                for (int i = 0; i < 4; ++i) {
                    int nn = qrow0 + g * 16 + lg * 4 + i;
                    out[((size_t)bb * SEQ + nn) * DIMC + hh * HDIM + db * 16 + lr] =
                        oacc[g][db][i] * rlq[i];
                }
        }
    }
}

// ---------------- launcher ----------------
extern "C" void kernel_launch(void* const* d_in, const int* in_sizes, int n_in,
                              void* d_out, int out_size, void* d_ws, size_t ws_size,
                              hipStream_t stream)
{
    const float* x  = (const float*)d_in[0];
    const float* Wq = (const float*)d_in[1];
    const float* bq = (const float*)d_in[2];
    const float* Wk = (const float*)d_in[3];
    const float* bk = (const float*)d_in[4];
    const float* Wv = (const float*)d_in[5];
    const float* bv = (const float*)d_in[6];
    float* out = (float*)d_out;

    char* ws = (char*)d_ws;
    _Float16* x16  = (_Float16*)ws;                          //  8 MB: [4096][1024]
    _Float16* wt   = (_Float16*)(ws + ((size_t)8  << 20));   //  6 MB: [3072][1024] (W^T)
    _Float16* q16  = (_Float16*)(ws + ((size_t)14 << 20));   //  8 MB: [b,h,n,d]
    _Float16* k16  = (_Float16*)(ws + ((size_t)22 << 20));   //  8 MB: [b,h,n,d]
    _Float16* vt16 = (_Float16*)(ws + ((size_t)30 << 20));   //  8 MB: [b,h,d,n]

    k_prep<<<4096 + 768, 256, 0, stream>>>(x, Wq, Wk, Wv, x16, wt);
    k_qkv_gemm<<<(MROWS / 128) * (NFEAT / 128), 256, 0, stream>>>(x16, wt, bq, bk, bv,
                                                                  q16, k16, vt16);
    k_attn<<<32 * (SEQ / 128), 512, 0, stream>>>(q16, k16, vt16, out);
}

// Round 16
// 84.225 us; speedup vs baseline: 1.1560x; 1.0835x over previous
//
#include <hip/hip_runtime.h>
#include <cstdint>
#include <cstddef>

// ---------------- constants ----------------
#define NB    2
#define SEQ   2048
#define DIMC  1024
#define NH    16
#define HDIM  64
#define MROWS (NB*SEQ)     // 4096
#define NFEAT (3*DIMC)     // 3072
#define KVBLK 64

typedef _Float16 half8 __attribute__((ext_vector_type(8)));
typedef _Float16 half4 __attribute__((ext_vector_type(4)));
typedef _Float16 half2v __attribute__((ext_vector_type(2)));
typedef __fp16   fp16x2 __attribute__((ext_vector_type(2)));
typedef float    f32x4 __attribute__((ext_vector_type(4)));

typedef const __attribute__((address_space(1))) void* gas_ptr;
typedef __attribute__((address_space(3))) void*       las_ptr;

__device__ __forceinline__ void gload_lds16(const void* g, void* l) {
    __builtin_amdgcn_global_load_lds((gas_ptr)g, (las_ptr)l, 16, 0, 0);
}

// v_exp_f32 computes 2^x directly (log2e folded into q-projection scale)
__device__ __forceinline__ float fast_exp2(float x) {
    float r;
    asm("v_exp_f32 %0, %1" : "=v"(r) : "v"(x));
    return r;
}

// pack two f32 -> two f16 (RTZ) in one instr; bit-cast to _Float16 vector
__device__ __forceinline__ half2v pk_f16(float a, float b) {
    fp16x2 r = __builtin_amdgcn_cvt_pkrtz(a, b);
    return __builtin_bit_cast(half2v, r);
}

// ---------------- kernel 1: fused input prep ----------------
// blocks [0,4096): x fp32 -> fp16 (vectorized)
// blocks [4096,4864): W[in][out] fp32 -> Wt[out][in] fp16 (LDS transpose)
__global__ __launch_bounds__(256) void k_prep(const float* __restrict__ x,
                                              const float* __restrict__ Wq,
                                              const float* __restrict__ Wk,
                                              const float* __restrict__ Wv,
                                              _Float16* __restrict__ x16,
                                              _Float16* __restrict__ wt) {
    __shared__ float tile[64][65];
    const int tid = threadIdx.x;
    if (blockIdx.x < 4096) {
        int i = (blockIdx.x * 256 + tid) * 4;
        float4 v = *reinterpret_cast<const float4*>(x + i);
        half4 h = { (_Float16)v.x, (_Float16)v.y, (_Float16)v.z, (_Float16)v.w };
        *reinterpret_cast<half4*>(x16 + i) = h;
        return;
    }
    const int bid  = blockIdx.x - 4096;   // 0..767
    const int midx = bid >> 8;            // which matrix
    const int t2   = bid & 255;           // 16x16 tiles of 64x64
    const int i0   = (t2 >> 4) * 64;      // input-row tile base
    const int o0   = (t2 & 15) * 64;      // output-feature tile base
    const float* W = (midx == 0) ? Wq : (midx == 1 ? Wk : Wv);
    #pragma unroll
    for (int p = 0; p < 4; ++p) {
        int id = p * 256 + tid;
        int r = id >> 4, c4 = (id & 15) * 4;
        float4 v = *reinterpret_cast<const float4*>(W + (size_t)(i0 + r) * DIMC + o0 + c4);
        tile[r][c4 + 0] = v.x; tile[r][c4 + 1] = v.y;
        tile[r][c4 + 2] = v.z; tile[r][c4 + 3] = v.w;
    }
    __syncthreads();
    #pragma unroll
    for (int p = 0; p < 4; ++p) {
        int id = p * 256 + tid;
        int oc = id >> 4, i4 = (id & 15) * 4;
        half4 h = { (_Float16)tile[i4 + 0][oc], (_Float16)tile[i4 + 1][oc],
                    (_Float16)tile[i4 + 2][oc], (_Float16)tile[i4 + 3][oc] };
        *reinterpret_cast<half4*>(wt + (size_t)(midx * DIMC + o0 + oc) * DIMC + i0 + i4) = h;
    }
}

// ---------------- kernel 2: fused QKV GEMM (256x256 tile, BK=64, 8-wave, phase-pipelined) ----------------
// C[4096,3072] = X16 @ Wt^T. 8 waves = 2(M) x 4(N); per-wave C block 128x64
// (acc 8x4 f32x4). LDS 128KB: A/B double-buffered K-tiles (256x64 f16 each),
// row&7-XOR chunk swizzle (proven 0-conflict), inverse-swizzled gload source.
// Per K-tile: 4 phases, each {stage 2 loads; ds_read A-frags; 16 MFMA
// (setprio); s_barrier}; the ONLY vmcnt wait is at phase 0 for loads issued
// a full K-tile earlier (counted-vmcnt mechanism: loads span 4 barriers).
__global__ __launch_bounds__(512, 2) void k_qkv_gemm(
    const _Float16* __restrict__ x16, const _Float16* __restrict__ wt,
    const float* __restrict__ bq, const float* __restrict__ bk, const float* __restrict__ bv,
    _Float16* __restrict__ q16, _Float16* __restrict__ k16, _Float16* __restrict__ vt16)
{
    __shared__ __align__(16) char lds[131072];
    // A: [0,64K) = buf*32K + slot*16 ; B: [64K,128K). Epilogue V-transpose reuses [0,70K).
    const int tid = threadIdx.x, lane = tid & 63, w = tid >> 6;
    const int wm = w >> 2, wn = w & 3;        // 2 x 4 wave grid
    const int lr = lane & 15, lg = lane >> 4;
    // XCD-bijective swizzle (192 % 8 == 0): each XCD gets 2 bm-rows x 12 bn
    const int swzb = (blockIdx.x & 7) * 24 + (blockIdx.x >> 3);
    const int bn = swzb % (NFEAT / 256);
    const int bm = swzb / (NFEAT / 256);
    const int m0 = bm * 256, n0 = bn * 256;

    const f32x4 zero4 = {0.f, 0.f, 0.f, 0.f};
    f32x4 acc[8][4];
    #pragma unroll
    for (int i = 0; i < 8; ++i)
        #pragma unroll
        for (int j = 0; j < 4; ++j) acc[i][j] = zero4;

    // stage unit l (of 4) for K-tile kt into buffer buf: 2 loads (A row + B row)
    auto stage2 = [&](int buf, int kt, int l) {
        int slot = l * 512 + tid;             // 0..2047
        int row  = slot >> 3;                 // 0..255
        int cg   = (slot & 7) ^ (row & 7);    // inverse-swizzled source chunk
        gload_lds16(x16 + (size_t)(m0 + row) * DIMC + kt * 64 + cg * 8,
                    lds + buf * 32768 + slot * 16);
        gload_lds16(wt  + (size_t)(n0 + row) * DIMC + kt * 64 + cg * 8,
                    lds + 65536 + buf * 32768 + slot * 16);
    };

    #pragma unroll
    for (int l = 0; l < 4; ++l) stage2(0, 0, l);

    half8 bf[4][2];
    for (int it = 0; it < 16; ++it) {
        const char* Ab = lds + (it & 1) * 32768;
        const char* Bb = lds + 65536 + (it & 1) * 32768;
        // wait for THIS K-tile's 8 loads (issued >= 4 barriers ago), then sync
        asm volatile("s_waitcnt vmcnt(0)" ::: "memory");
        __builtin_amdgcn_s_barrier();
        #pragma unroll
        for (int p = 0; p < 4; ++p) {
            if (it + 1 < 16) stage2((it + 1) & 1, it + 1, p);
            if (p == 0) {
                // B-frags read once per K-tile, held in registers
                #pragma unroll
                for (int nb = 0; nb < 4; ++nb) {
                    int col = wn * 64 + nb * 16 + lr;
                    #pragma unroll
                    for (int kk = 0; kk < 2; ++kk)
                        bf[nb][kk] = *(const half8*)(Bb + col * 128
                                        + (((kk * 4 + lg) ^ (col & 7)) << 4));
                }
            }
            half8 af[2][2];
            #pragma unroll
            for (int m2 = 0; m2 < 2; ++m2) {
                int row = wm * 128 + (p * 2 + m2) * 16 + lr;
                #pragma unroll
                for (int kk = 0; kk < 2; ++kk)
                    af[m2][kk] = *(const half8*)(Ab + row * 128
                                    + (((kk * 4 + lg) ^ (row & 7)) << 4));
            }
            __builtin_amdgcn_s_setprio(1);
            #pragma unroll
            for (int m2 = 0; m2 < 2; ++m2)
                #pragma unroll
                for (int nb = 0; nb < 4; ++nb) {
                    acc[p * 2 + m2][nb] = __builtin_amdgcn_mfma_f32_16x16x32_f16(
                        af[m2][0], bf[nb][0], acc[p * 2 + m2][nb], 0, 0, 0);
                    acc[p * 2 + m2][nb] = __builtin_amdgcn_mfma_f32_16x16x32_f16(
                        af[m2][1], bf[nb][1], acc[p * 2 + m2][nb], 0, 0, 0);
                }
            __builtin_amdgcn_s_setprio(0);
            if (p < 3) __builtin_amdgcn_s_barrier();
        }
    }

    const int sec = n0 >> 10;                 // 0=q 1=k 2=v (256 | 1024, one section/block)
    const float* bias = (sec == 0) ? bq : (sec == 1 ? bk : bv);
    const float scl = (sec == 0) ? 0.125f * 1.44269504088896f : 1.0f;
    float bfv[4];
    #pragma unroll
    for (int nb = 0; nb < 4; ++nb)
        bfv[nb] = bias[(n0 & 1023) + wn * 64 + nb * 16 + lr];

    if (sec < 2) {
        _Float16* dst = (sec == 0) ? q16 : k16;
        #pragma unroll
        for (int mb = 0; mb < 8; ++mb)
            #pragma unroll
            for (int i2 = 0; i2 < 4; ++i2) {
                int rg = m0 + wm * 128 + mb * 16 + lg * 4 + i2;
                int bb = rg >> 11, nn = rg & (SEQ - 1);
                #pragma unroll
                for (int nb = 0; nb < 4; ++nb) {
                    int f1 = (n0 & 1023) + wn * 64 + nb * 16 + lr;
                    int hh = f1 >> 6, dd = f1 & 63;
                    dst[((size_t)(bb * NH + hh) * SEQ + nn) * HDIM + dd] =
                        (_Float16)((acc[mb][nb][i2] + bfv[nb]) * scl);
                }
            }
    } else {
        // V: transpose 256x256 tile through LDS in two 128-row passes,
        // write vT[b,h,d,n] coalesced. lt: [256 cols][136 halfs] = 69632 B.
        __syncthreads();
        char* lt = lds;
        #pragma unroll
        for (int pass = 0; pass < 2; ++pass) {
            if (wm == pass) {
                #pragma unroll
                for (int mb = 0; mb < 8; ++mb)
                    #pragma unroll
                    for (int nb = 0; nb < 4; ++nb) {
                        int c  = wn * 64 + nb * 16 + lr;
                        int r0 = mb * 16 + lg * 4;
                        half4 hv = { (_Float16)(acc[mb][nb][0] + bfv[nb]),
                                     (_Float16)(acc[mb][nb][1] + bfv[nb]),
                                     (_Float16)(acc[mb][nb][2] + bfv[nb]),
                                     (_Float16)(acc[mb][nb][3] + bfv[nb]) };
                        *(half4*)(lt + c * 272 + r0 * 2) = hv;
                    }
            }
            __syncthreads();
            #pragma unroll
            for (int u = 0; u < 8; ++u) {
                int id = u * 512 + tid;        // 0..4095
                int c = id >> 4, r8 = (id & 15) * 8;
                half8 hv = *(const half8*)(lt + c * 272 + r8 * 2);
                int f1 = (n0 & 1023) + c;
                int hh = f1 >> 6, dd = f1 & 63;
                int rg = m0 + pass * 128 + r8;
                int bb = rg >> 11, nn = rg & (SEQ - 1);
                *(half8*)(vt16 + ((size_t)(bb * NH + hh) * HDIM + dd) * SEQ + nn) = hv;
            }
            __syncthreads();
        }
    }
}

// ---------------- kernel 3: flash attention (round-12 proven best) ----------------
// 512 thr = 8 waves, QBLK=128, split-KV wave pairs (waves 0-3: tiles 0-15,
// waves 4-7: tiles 16-31, same q; each wave: two 16-row q-groups). Max-free
// softmax (P=2^s unnormalized, divide at end). Conflict-free P roundtrip.
__global__ __launch_bounds__(512, 4) void k_attn(
    const _Float16* __restrict__ q16, const _Float16* __restrict__ k16,
    const _Float16* __restrict__ vt16, float* __restrict__ out)
{
    __shared__ __align__(16) char lds[81920];
    // [0,16K) K_A dbuf | [16K,32K) K_B dbuf | [32K,48K) V_A dbuf | [48K,64K) V_B dbuf
    // [64K,80K) P: 8 waves x 2KB (reused by both q-groups sequentially)
    // epilogue exchange reuses [0, 40960)
    const int tid = threadIdx.x, lane = tid & 63, w = tid >> 6;
    const int lr = lane & 15, lg = lane >> 4;
    const int sub = w >> 2;                   // KV half
    const int qg  = w & 3;                    // 32-row q sub-block
    // XCD-bijective swizzle (512 % 8 == 0)
    const int swz = (blockIdx.x & 7) * 64 + (blockIdx.x >> 3);
    const int bh = swz >> 4;                  // 0..31
    const int qt = swz & 15;                  // 0..15
    const int qrow0 = qt * 128 + qg * 32;
    const _Float16* qh = q16 + (size_t)bh * SEQ * HDIM;
    const _Float16* kh = k16 + (size_t)bh * SEQ * HDIM;
    const _Float16* vh = vt16 + (size_t)bh * HDIM * SEQ;
    char* pl = lds + 65536 + w * 2048;
    const int rb = lr >> 3;                   // row bit 3 -> 8B slot parity

    // staging: 512 threads x 4 x 16B = 32KB per phase (K/V for both streams)
    const int srow = tid >> 3;                // 0..63
    const int scg  = (tid & 7) ^ (srow & 7);  // inverse-swizzled source chunk

    auto stageKV = [&](int buf, int t) {
        const int jA = t * KVBLK, jB = (16 + t) * KVBLK;
        gload_lds16(kh + (size_t)(jA + srow) * HDIM + scg * 8,
                    lds + buf * 8192 + tid * 16);
        gload_lds16(kh + (size_t)(jB + srow) * HDIM + scg * 8,
                    lds + 16384 + buf * 8192 + tid * 16);
        gload_lds16(vh + (size_t)srow * SEQ + jA + scg * 8,
                    lds + 32768 + buf * 8192 + tid * 16);
        gload_lds16(vh + (size_t)srow * SEQ + jB + scg * 8,
                    lds + 49152 + buf * 8192 + tid * 16);
    };

    half8 aq[2][2];
    #pragma unroll
    for (int g = 0; g < 2; ++g)
        #pragma unroll
        for (int kc = 0; kc < 2; ++kc)
            aq[g][kc] = *(const half8*)(qh + (size_t)(qrow0 + g * 16 + lr) * HDIM + kc * 32 + lg * 8);

    const f32x4 zero4 = {0.f, 0.f, 0.f, 0.f};
    f32x4 l4[2] = { zero4, zero4 };
    f32x4 oacc[2][4];
    #pragma unroll
    for (int g = 0; g < 2; ++g)
        #pragma unroll
        for (int i = 0; i < 4; ++i) oacc[g][i] = zero4;

    stageKV(0, 0);
    for (int t = 0; t < 16; ++t) {
        __syncthreads();                      // buf[t&1] ready (drains vmcnt)
        if (t + 1 < 16) stageKV((t + 1) & 1, t + 1);
        const char* Kb = lds + sub * 16384 + (t & 1) * 8192;
        const char* Vb = lds + 32768 + sub * 16384 + (t & 1) * 8192;

        // swapped QK^T for both q-groups; K fragments read ONCE
        f32x4 s0[4], s1[4];
        __builtin_amdgcn_s_setprio(1);
        #pragma unroll
        for (int jb = 0; jb < 4; ++jb) {
            int row = jb * 16 + lr;
            half8 k0 = *(const half8*)(Kb + row * 128 + (((0 + lg) ^ (row & 7)) << 4));
            half8 k1 = *(const half8*)(Kb + row * 128 + (((4 + lg) ^ (row & 7)) << 4));
            f32x4 a0 = __builtin_amdgcn_mfma_f32_16x16x32_f16(k0, aq[0][0], zero4, 0, 0, 0);
            f32x4 a1 = __builtin_amdgcn_mfma_f32_16x16x32_f16(k0, aq[1][0], zero4, 0, 0, 0);
            a0 = __builtin_amdgcn_mfma_f32_16x16x32_f16(k1, aq[0][1], a0, 0, 0, 0);
            a1 = __builtin_amdgcn_mfma_f32_16x16x32_f16(k1, aq[1][1], a1, 0, 0, 0);
            s0[jb] = a0; s1[jb] = a1;
        }
        __builtin_amdgcn_s_setprio(0);

        // group 0: max-free softmax + pack + P write
        #pragma unroll
        for (int jb = 0; jb < 4; ++jb) {
            #pragma unroll
            for (int i = 0; i < 4; ++i) s0[jb][i] = fast_exp2(s0[jb][i]);
            l4[0] += s0[jb];
            half2v w0 = pk_f16(s0[jb][0], s0[jb][1]);
            half2v w1 = pk_f16(s0[jb][2], s0[jb][3]);
            half4 pk = { w0.x, w0.y, w1.x, w1.y };
            *(half4*)(pl + lr * 128 + (((jb * 2 + (lg >> 1)) ^ (lr & 7)) << 4)
                      + (((lg & 1) ^ rb) << 3)) = pk;
        }
        // group 1: softmax + pack to regs (write after g0's P is read back)
        half4 pk1[4];
        #pragma unroll
        for (int jb = 0; jb < 4; ++jb) {
            #pragma unroll
            for (int i = 0; i < 4; ++i) s1[jb][i] = fast_exp2(s1[jb][i]);
            l4[1] += s1[jb];
            half2v w0 = pk_f16(s1[jb][0], s1[jb][1]);
            half2v w1 = pk_f16(s1[jb][2], s1[jb][3]);
            pk1[jb] = half4{ w0.x, w0.y, w1.x, w1.y };
        }
        asm volatile("s_waitcnt lgkmcnt(0)" ::: "memory");
        const char* prow = pl + lr * 128;
        half8 ap[2][2];
        {
            half4 l0 = *(const half4*)(prow + (((0 + lg) ^ (lr & 7)) << 4) + (rb << 3));
            half4 h0 = *(const half4*)(prow + (((0 + lg) ^ (lr & 7)) << 4) + ((1 ^ rb) << 3));
            half4 l1 = *(const half4*)(prow + (((4 + lg) ^ (lr & 7)) << 4) + (rb << 3));
            half4 h1 = *(const half4*)(prow + (((4 + lg) ^ (lr & 7)) << 4) + ((1 ^ rb) << 3));
            ap[0][0] = half8{ l0.x, l0.y, l0.z, l0.w, h0.x, h0.y, h0.z, h0.w };
            ap[0][1] = half8{ l1.x, l1.y, l1.z, l1.w, h1.x, h1.y, h1.z, h1.w };
        }
        // write group 1 P (same buffer; DS pipe is in-order within a wave)
        #pragma unroll
        for (int jb = 0; jb < 4; ++jb)
            *(half4*)(pl + lr * 128 + (((jb * 2 + (lg >> 1)) ^ (lr & 7)) << 4)
                      + (((lg & 1) ^ rb) << 3)) = pk1[jb];
        asm volatile("s_waitcnt lgkmcnt(0)" ::: "memory");
        {
            half4 l0 = *(const half4*)(prow + (((0 + lg) ^ (lr & 7)) << 4) + (rb << 3));
            half4 h0 = *(const half4*)(prow + (((0 + lg) ^ (lr & 7)) << 4) + ((1 ^ rb) << 3));
            half4 l1 = *(const half4*)(prow + (((4 + lg) ^ (lr & 7)) << 4) + (rb << 3));
            half4 h1 = *(const half4*)(prow + (((4 + lg) ^ (lr & 7)) << 4) + ((1 ^ rb) << 3));
            ap[1][0] = half8{ l0.x, l0.y, l0.z, l0.w, h0.x, h0.y, h0.z, h0.w };
            ap[1][1] = half8{ l1.x, l1.y, l1.z, l1.w, h1.x, h1.y, h1.z, h1.w };
        }
        // PV: V fragments read lazily (once, feed both groups)
        __builtin_amdgcn_s_setprio(1);
        #pragma unroll
        for (int db = 0; db < 4; ++db) {
            int row = db * 16 + lr;
            half8 vf0 = *(const half8*)(Vb + row * 128 + (((0 + lg) ^ (row & 7)) << 4));
            half8 vf1 = *(const half8*)(Vb + row * 128 + (((4 + lg) ^ (row & 7)) << 4));
            oacc[0][db] = __builtin_amdgcn_mfma_f32_16x16x32_f16(ap[0][0], vf0, oacc[0][db], 0, 0, 0);
            oacc[1][db] = __builtin_amdgcn_mfma_f32_16x16x32_f16(ap[1][0], vf0, oacc[1][db], 0, 0, 0);
            oacc[0][db] = __builtin_amdgcn_mfma_f32_16x16x32_f16(ap[0][1], vf1, oacc[0][db], 0, 0, 0);
            oacc[1][db] = __builtin_amdgcn_mfma_f32_16x16x32_f16(ap[1][1], vf1, oacc[1][db], 0, 0, 0);
        }
        __builtin_amdgcn_s_setprio(0);
    }

    // ---- cross-pair reduction: wave w (sub=1) -> wave w^4 (sub=0) ----
    __syncthreads();                          // all tile compute done
    char* xch = lds;                          // [0, 8*5120) = 40960B
    if (sub == 1) {
        char* sl = xch + (qg * 2) * 5120;
        #pragma unroll
        for (int g = 0; g < 2; ++g) {
            #pragma unroll
            for (int db = 0; db < 4; ++db)
                *(f32x4*)(sl + g * 5120 + db * 1024 + lane * 16) = oacc[g][db];
            *(f32x4*)(sl + g * 5120 + 4096 + lane * 16) = l4[g];
        }
    }
    __syncthreads();
    if (sub == 0) {
        char* sl = xch + (qg * 2) * 5120;
        #pragma unroll
        for (int g = 0; g < 2; ++g) {
            #pragma unroll
            for (int db = 0; db < 4; ++db)
                oacc[g][db] += *(const f32x4*)(sl + g * 5120 + db * 1024 + lane * 16);
            l4[g] += *(const f32x4*)(sl + g * 5120 + 4096 + lane * 16);
        }
        const int bb = bh >> 4, hh = bh & 15;
        #pragma unroll
        for (int g = 0; g < 2; ++g) {
            float l_i = (l4[g][0] + l4[g][1]) + (l4[g][2] + l4[g][3]);
            l_i += __shfl_xor(l_i, 16);
            l_i += __shfl_xor(l_i, 32);
            float rlq[4];
            #pragma unroll
            for (int i = 0; i < 4; ++i)
                rlq[i] = 1.0f / __shfl(l_i, lg * 4 + i);
            #pragma unroll
            for (int db = 0; db < 4; ++db)
                #pragma unroll
                for (int i = 0; i < 4; ++i) {
                    int nn = qrow0 + g * 16 + lg * 4 + i;
                    out[((size_t)bb * SEQ + nn) * DIMC + hh * HDIM + db * 16 + lr] =
                        oacc[g][db][i] * rlq[i];
                }
        }
    }
}

// ---------------- launcher ----------------
extern "C" void kernel_launch(void* const* d_in, const int* in_sizes, int n_in,
                              void* d_out, int out_size, void* d_ws, size_t ws_size,
                              hipStream_t stream)
{
    const float* x  = (const float*)d_in[0];
    const float* Wq = (const float*)d_in[1];
    const float* bq = (const float*)d_in[2];
    const float* Wk = (const float*)d_in[3];
    const float* bk = (const float*)d_in[4];
    const float* Wv = (const float*)d_in[5];
    const float* bv = (const float*)d_in[6];
    float* out = (float*)d_out;

    char* ws = (char*)d_ws;
    _Float16* x16  = (_Float16*)ws;                          //  8 MB: [4096][1024]
    _Float16* wt   = (_Float16*)(ws + ((size_t)8  << 20));   //  6 MB: [3072][1024] (W^T)
    _Float16* q16  = (_Float16*)(ws + ((size_t)14 << 20));   //  8 MB: [b,h,n,d]
    _Float16* k16  = (_Float16*)(ws + ((size_t)22 << 20));   //  8 MB: [b,h,n,d]
    _Float16* vt16 = (_Float16*)(ws + ((size_t)30 << 20));   //  8 MB: [b,h,d,n]

    k_prep<<<4096 + 768, 256, 0, stream>>>(x, Wq, Wk, Wv, x16, wt);
    k_qkv_gemm<<<(MROWS / 256) * (NFEAT / 256), 512, 0, stream>>>(x16, wt, bq, bk, bv,
                                                                  q16, k16, vt16);
    k_attn<<<32 * (SEQ / 128), 512, 0, stream>>>(q16, k16, vt16, out);
}